// Round 1
// 368.350 us; speedup vs baseline: 1.0995x; 1.0995x over previous
//
#include <hip/hip_runtime.h>
#include <math.h>

#define N_NODES 8192
#define F_IN 512
#define NH1 8
#define C1 8
#define D1 64   // NH1*C1
#define NC 16
#define E_EDGES 262144
#define TOT_EDGES (E_EDGES + N_NODES)
#define NEG_SLOPE 0.2f
#define CAP 128   // per-node edge cache capacity (max degree ~65 incl self-loop)

// ---- GEMM1 + fused logits1: h1pre[N,64] = x @ W1; als1/ald1[N,8] -------------
// BM=32 -> 256 blocks (all CUs busy). Thread tile 2x4.
__global__ __launch_bounds__(256) void gemm1_k(const float* __restrict__ x,
                                               const float* __restrict__ W1,
                                               const float* __restrict__ a_src1,
                                               const float* __restrict__ a_dst1,
                                               float* __restrict__ h1pre,
                                               float* __restrict__ als1,
                                               float* __restrict__ ald1) {
    __shared__ __align__(16) float As[32 * 34];  // [k=32][m=32 +2 pad] (8B-aligned f2 reads)
    __shared__ __align__(16) float Bs[32 * 68];  // [k=32][n=64 +4 pad]
    int tid = threadIdx.x;
    int rowBase = blockIdx.x * 32;
    int rm = tid >> 4, rn = tid & 15;            // rows rm*2.., cols rn*4..
    float acc[2][4] = {};
    for (int k0 = 0; k0 < F_IN; k0 += 32) {
#pragma unroll
        for (int j = 0; j < 4; ++j) {            // A tile: 32 rows x 32 k
            int i = tid + 256 * j;
            int r = i >> 5, c = i & 31;
            As[c * 34 + r] = x[(rowBase + r) * F_IN + k0 + c];
        }
#pragma unroll
        for (int j = 0; j < 8; ++j) {            // B tile: 32 k x 64 cols
            int i = tid + 256 * j;
            int rr = i >> 6, cc = i & 63;
            Bs[rr * 68 + cc] = W1[(k0 + rr) * D1 + cc];
        }
        __syncthreads();
#pragma unroll
        for (int kk = 0; kk < 32; ++kk) {
            float2 a = *(const float2*)&As[kk * 34 + rm * 2];
            float4 b = *(const float4*)&Bs[kk * 68 + rn * 4];
            float av[2] = {a.x, a.y};
            float bv[4] = {b.x, b.y, b.z, b.w};
#pragma unroll
            for (int jj = 0; jj < 2; ++jj)
#pragma unroll
                for (int ll = 0; ll < 4; ++ll)
                    acc[jj][ll] = fmaf(av[jj], bv[ll], acc[jj][ll]);
        }
        __syncthreads();
    }
    int h = rn >> 1, half = rn & 1;
#pragma unroll
    for (int jj = 0; jj < 2; ++jj) {
        int row = rowBase + rm * 2 + jj;
        float4 o = {acc[jj][0], acc[jj][1], acc[jj][2], acc[jj][3]};
        *(float4*)&h1pre[(size_t)row * D1 + rn * 4] = o;
        // fused logits1: partial per-head dot, pair-reduce across rn^1
        float ps = 0.f, pd = 0.f;
#pragma unroll
        for (int ll = 0; ll < 4; ++ll) {
            ps = fmaf(acc[jj][ll], a_src1[h * C1 + half * 4 + ll], ps);
            pd = fmaf(acc[jj][ll], a_dst1[h * C1 + half * 4 + ll], pd);
        }
        ps += __shfl_xor(ps, 1);
        pd += __shfl_xor(pd, 1);
        if (half == 0) {
            als1[row * NH1 + h] = ps;
            ald1[row * NH1 + h] = pd;
        }
    }
}

// ---------------- CSR build: histogram / scan / scatter ----------------
__global__ void hist_k(const int* __restrict__ ei, int* __restrict__ counts) {
    int i = blockIdx.x * blockDim.x + threadIdx.x;
    if (i >= TOT_EDGES) return;
    int dst = (i < E_EDGES) ? ei[E_EDGES + i] : (i - E_EDGES);
    atomicAdd(&counts[dst], 1);
}

__global__ __launch_bounds__(1024) void scan_k(const int* __restrict__ counts,
                                               int* __restrict__ offsets, int* __restrict__ cursor) {
    __shared__ int wtot[16];
    __shared__ int wbase[16];
    int t = threadIdx.x;
    int lane = t & 63, wid = t >> 6;
    int local[8];
    int s = 0;
#pragma unroll
    for (int j = 0; j < 8; ++j) { local[j] = counts[t * 8 + j]; s += local[j]; }
    // wave-level inclusive scan via shfl
    int incl = s;
#pragma unroll
    for (int d = 1; d < 64; d <<= 1) {
        int v = __shfl_up(incl, d);
        if (lane >= d) incl += v;
    }
    if (lane == 63) wtot[wid] = incl;
    __syncthreads();
    if (t < 16) {
        int v = wtot[t];
        int iv = v;
#pragma unroll
        for (int d = 1; d < 16; d <<= 1) {
            int u = __shfl_up(iv, d);
            if (t >= d) iv += u;
        }
        wbase[t] = iv - v;   // exclusive
    }
    __syncthreads();
    int run = wbase[wid] + incl - s;   // exclusive prefix for this thread
#pragma unroll
    for (int j = 0; j < 8; ++j) {
        offsets[t * 8 + j] = run;
        cursor[t * 8 + j] = run;
        run += local[j];
    }
    if (t == 1023) offsets[8192] = run;
}

__global__ void scatter_k(const int* __restrict__ ei, int* __restrict__ cursor, int* __restrict__ csr) {
    int i = blockIdx.x * blockDim.x + threadIdx.x;
    if (i >= TOT_EDGES) return;
    int src, dst;
    if (i < E_EDGES) { src = ei[i]; dst = ei[E_EDGES + i]; }
    else             { src = i - E_EDGES; dst = src; }
    int pos = atomicAdd(&cursor[dst], 1);
    csr[pos] = src;
}

// -- Layer-1 softmax+agg, fused ELU + gemm2 + logits2; one wave per dst node --
__global__ __launch_bounds__(64) void agg1_k(const float* __restrict__ h1pre,
                                             const float* __restrict__ als1, const float* __restrict__ ald1,
                                             const int* __restrict__ offsets, const int* __restrict__ csr,
                                             const float* __restrict__ b1,
                                             const float* __restrict__ W2,
                                             const float* __restrict__ a_src2, const float* __restrict__ a_dst2,
                                             float* __restrict__ h2pre,
                                             float* __restrict__ als2, float* __restrict__ ald2) {
    __shared__ int   csr_s[CAP];
    __shared__ float vbuf[CAP * NH1];
    __shared__ float vals[64];
    int n = blockIdx.x, t = threadIdx.x;
    int beg = offsets[n], end = offsets[n + 1];
    int deg = end - beg;
    float val;
    if (deg <= CAP) {
        int h = t & 7, eo = t >> 3;              // 8 edges in flight x 8 heads
        float aldh = ald1[n * NH1 + h];
        float m = -3.4e38f;
        for (int e = eo; e < deg; e += 8) {
            int s = csr[beg + e];
            if (h == 0) csr_s[e] = s;
            float v = als1[s * NH1 + h] + aldh;
            v = v > 0.f ? v : NEG_SLOPE * v;
            vbuf[e * NH1 + h] = v;
            m = fmaxf(m, v);
        }
        m = fmaxf(m, __shfl_xor(m, 8));
        m = fmaxf(m, __shfl_xor(m, 16));
        m = fmaxf(m, __shfl_xor(m, 32));
        float den = 0.f;
        for (int e = eo; e < deg; e += 8) {
            float w = expf(vbuf[e * NH1 + h] - m);
            vbuf[e * NH1 + h] = w;               // cache the weight
            den += w;
        }
        den += __shfl_xor(den, 8);
        den += __shfl_xor(den, 16);
        den += __shfl_xor(den, 32);
        __syncthreads();
        // aggregation: lane t owns output column t, head q = t>>3
        int q = t >> 3;
        float dq = __shfl(den, q);
        float acc = 0.f;
        int e = 0;
        for (; e + 4 <= deg; e += 4) {           // 4 gathers in flight
            int s0 = csr_s[e], s1 = csr_s[e + 1], s2 = csr_s[e + 2], s3 = csr_s[e + 3];
            float w0 = vbuf[e * NH1 + q], w1 = vbuf[(e + 1) * NH1 + q];
            float w2 = vbuf[(e + 2) * NH1 + q], w3 = vbuf[(e + 3) * NH1 + q];
            acc = fmaf(w0, h1pre[s0 * D1 + t], acc);
            acc = fmaf(w1, h1pre[s1 * D1 + t], acc);
            acc = fmaf(w2, h1pre[s2 * D1 + t], acc);
            acc = fmaf(w3, h1pre[s3 * D1 + t], acc);
        }
        for (; e < deg; ++e)
            acc = fmaf(vbuf[e * NH1 + q], h1pre[csr_s[e] * D1 + t], acc);
        val = acc / dq + b1[t];
    } else {
        // fallback: original recompute path (uniform branch, rare)
        int h = t & 7;
        float aldh = ald1[n * NH1 + h];
        float m = -3.4e38f;
        for (int i = beg + (t >> 3); i < end; i += 8) {
            int s = csr[i];
            float v = als1[s * NH1 + h] + aldh;
            v = v > 0.f ? v : NEG_SLOPE * v;
            m = fmaxf(m, v);
        }
        m = fmaxf(m, __shfl_xor(m, 8));
        m = fmaxf(m, __shfl_xor(m, 16));
        m = fmaxf(m, __shfl_xor(m, 32));
        float den = 0.f;
        for (int i = beg + (t >> 3); i < end; i += 8) {
            int s = csr[i];
            float v = als1[s * NH1 + h] + aldh;
            v = v > 0.f ? v : NEG_SLOPE * v;
            den += expf(v - m);
        }
        den += __shfl_xor(den, 8);
        den += __shfl_xor(den, 16);
        den += __shfl_xor(den, 32);
        int q = t >> 3;
        float mq = __shfl(m, q);
        float dq = __shfl(den, q);
        float aldq = ald1[n * NH1 + q];
        float acc = 0.f;
        for (int i = beg; i < end; ++i) {
            int s = csr[i];
            float v = als1[s * NH1 + q] + aldq;
            v = v > 0.f ? v : NEG_SLOPE * v;
            acc = fmaf(expf(v - mq), h1pre[s * D1 + t], acc);
        }
        val = acc / dq + b1[t];
    }
    val = val > 0.f ? val : expm1f(val);         // ELU -> out1[n][t] in-register
    // ---- fused gemm2 + logits2: h2[c] = sum_t out1[t]*W2[t][c] ----
    __syncthreads();
    vals[t] = val;
    __syncthreads();
    int g = t >> 4, c = t & 15;                  // 4 k-groups x 16 channels
    float a2 = 0.f;
    const float* w2p = W2 + g * 16 * NC + c;
#pragma unroll
    for (int j = 0; j < 16; ++j)
        a2 = fmaf(vals[g * 16 + j], w2p[j * NC], a2);
    a2 += __shfl_xor(a2, 16);
    a2 += __shfl_xor(a2, 32);                    // all lanes: h2pre[n][c], c=t&15
    if (t < 16) h2pre[(size_t)n * NC + t] = a2;
    float ps = a2 * a_src2[c], pd = a2 * a_dst2[c];
#pragma unroll
    for (int d = 1; d < 16; d <<= 1) {
        ps += __shfl_xor(ps, d);
        pd += __shfl_xor(pd, d);
    }
    if (t == 0) { als2[n] = ps; ald2[n] = pd; }
}

// ------- Layer-2 softmax + agg + bias + fused log_softmax, one wave/node -------
__global__ __launch_bounds__(64) void agg2_k(const float* __restrict__ h2pre,
                                             const float* __restrict__ als2, const float* __restrict__ ald2,
                                             const int* __restrict__ offsets, const int* __restrict__ csr,
                                             const float* __restrict__ b2,
                                             float* __restrict__ z, float* __restrict__ out_ls) {
    __shared__ int   csr2[CAP];
    __shared__ float wb2[CAP];
    int n = blockIdx.x, t = threadIdx.x;
    int beg = offsets[n], end = offsets[n + 1];
    int deg = end - beg;
    float aldn = ald2[n];
    int eg = t >> 4, c = t & 15;                 // 4 edge-groups x 16 channels
    float zv;
    if (deg <= CAP) {
        float m = -3.4e38f;
        for (int i = t; i < deg; i += 64) {
            int s = csr[beg + i];
            csr2[i] = s;
            float v = als2[s] + aldn;
            v = v > 0.f ? v : NEG_SLOPE * v;
            wb2[i] = v;
            m = fmaxf(m, v);
        }
#pragma unroll
        for (int d = 1; d < 64; d <<= 1) m = fmaxf(m, __shfl_xor(m, d));
        float den = 0.f;
        for (int i = t; i < deg; i += 64) {
            float w = expf(wb2[i] - m);
            wb2[i] = w;
            den += w;
        }
#pragma unroll
        for (int d = 1; d < 64; d <<= 1) den += __shfl_xor(den, d);
        __syncthreads();
        float acc = 0.f;
        int e = eg;
        for (; e + 4 < deg; e += 8) {            // 2 gathers in flight per group
            int s0 = csr2[e], s1 = csr2[e + 4];
            float w0 = wb2[e], w1 = wb2[e + 4];
            acc = fmaf(w0, h2pre[s0 * NC + c], acc);
            acc = fmaf(w1, h2pre[s1 * NC + c], acc);
        }
        for (; e < deg; e += 4)
            acc = fmaf(wb2[e], h2pre[csr2[e] * NC + c], acc);
        acc += __shfl_xor(acc, 16);
        acc += __shfl_xor(acc, 32);
        zv = acc / den + b2[c];
    } else {
        float m = -3.4e38f;
        for (int i = beg + t; i < end; i += 64) {
            float v = als2[csr[i]] + aldn;
            v = v > 0.f ? v : NEG_SLOPE * v;
            m = fmaxf(m, v);
        }
#pragma unroll
        for (int d = 1; d < 64; d <<= 1) m = fmaxf(m, __shfl_xor(m, d));
        float den = 0.f;
        for (int i = beg + t; i < end; i += 64) {
            float v = als2[csr[i]] + aldn;
            v = v > 0.f ? v : NEG_SLOPE * v;
            den += expf(v - m);
        }
#pragma unroll
        for (int d = 1; d < 64; d <<= 1) den += __shfl_xor(den, d);
        float acc = 0.f;
        for (int i = beg + eg; i < end; i += 4) {
            int s = csr[i];
            float v = als2[s] + aldn;
            v = v > 0.f ? v : NEG_SLOPE * v;
            acc = fmaf(expf(v - m), h2pre[(size_t)s * NC + c], acc);
        }
        acc += __shfl_xor(acc, 16);
        acc += __shfl_xor(acc, 32);
        zv = acc / den + b2[c];
    }
    if (t < 16) z[(size_t)n * NC + t] = zv;
    // log_softmax over the 16 channels (xor 1,2,4,8 stays within 16-lane groups)
    float zm = zv;
#pragma unroll
    for (int d = 1; d < 16; d <<= 1) zm = fmaxf(zm, __shfl_xor(zm, d));
    float se = expf(zv - zm);
#pragma unroll
    for (int d = 1; d < 16; d <<= 1) se += __shfl_xor(se, d);
    if (t < 16) out_ls[(size_t)n * NC + t] = zv - (zm + logf(se));
}

// ---------------- Gram: out[8192,8192] = z @ z^T ----------------
__global__ __launch_bounds__(256) void gram_k(const float* __restrict__ z,
                                              float* __restrict__ out) {
    __shared__ __align__(16) float rz[64 * 16];   // 64 row vectors
    int tid = threadIdx.x;
    int colBase = blockIdx.x * 256;
    int rowBase = blockIdx.y * 64;
    ((float4*)rz)[tid] = ((const float4*)z)[rowBase * 4 + tid];
    int j = colBase + tid;
    float c[16];
#pragma unroll
    for (int k4 = 0; k4 < 4; ++k4) {
        float4 v = ((const float4*)(z + (size_t)j * 16))[k4];
        c[k4 * 4 + 0] = v.x; c[k4 * 4 + 1] = v.y; c[k4 * 4 + 2] = v.z; c[k4 * 4 + 3] = v.w;
    }
    __syncthreads();
#pragma unroll 4
    for (int r = 0; r < 64; ++r) {
        const float* zr = &rz[r * 16];
        float acc = 0.f;
#pragma unroll
        for (int k = 0; k < 16; ++k) acc = fmaf(c[k], zr[k], acc);
        out[(size_t)(rowBase + r) * N_NODES + j] = acc;
    }
}

extern "C" void kernel_launch(void* const* d_in, const int* in_sizes, int n_in,
                              void* d_out, int out_size, void* d_ws, size_t ws_size,
                              hipStream_t stream) {
    (void)in_sizes; (void)n_in; (void)out_size; (void)ws_size;
    const float* x      = (const float*)d_in[0];
    const int*   ei     = (const int*)d_in[1];
    const float* W1     = (const float*)d_in[2];
    const float* a_src1 = (const float*)d_in[3];
    const float* a_dst1 = (const float*)d_in[4];
    const float* b1     = (const float*)d_in[5];
    const float* W2     = (const float*)d_in[6];
    const float* a_src2 = (const float*)d_in[7];
    const float* a_dst2 = (const float*)d_in[8];
    const float* b2     = (const float*)d_in[9];
    float* out = (float*)d_out;

    char* ws = (char*)d_ws;                    // all offsets 256B-aligned
    float* h1pre  = (float*)(ws + 0);          // 2 MB
    // (out1 slot at +2 MB now unused: out1 lives in registers inside agg1_k)
    float* als1   = (float*)(ws + 4194304);    // 256 KB
    float* ald1   = (float*)(ws + 4456448);    // 256 KB
    float* h2pre  = (float*)(ws + 4718592);    // 512 KB
    float* als2   = (float*)(ws + 5242880);    // 32 KB
    float* ald2   = (float*)(ws + 5275648);    // 32 KB
    float* zarr   = (float*)(ws + 5308416);    // 512 KB
    int*   counts = (int*)  (ws + 5832704);    // 32 KB
    int*   offsets= (int*)  (ws + 5865472);    // 8193 ints
    int*   cursor = (int*)  (ws + 5898496);    // 32 KB
    int*   csr    = (int*)  (ws + 5931264);    // 1.03 MB

    hipMemsetAsync(counts, 0, N_NODES * sizeof(int), stream);
    hist_k<<<(TOT_EDGES + 255) / 256, 256, 0, stream>>>(ei, counts);
    scan_k<<<1, 1024, 0, stream>>>(counts, offsets, cursor);
    scatter_k<<<(TOT_EDGES + 255) / 256, 256, 0, stream>>>(ei, cursor, csr);

    gemm1_k<<<N_NODES / 32, 256, 0, stream>>>(x, W1, a_src1, a_dst1, h1pre, als1, ald1);
    agg1_k<<<N_NODES, 64, 0, stream>>>(h1pre, als1, ald1, offsets, csr, b1,
                                       W2, a_src2, a_dst2, h2pre, als2, ald2);
    agg2_k<<<N_NODES, 64, 0, stream>>>(h2pre, als2, ald2, offsets, csr, b2, zarr, out);

    gram_k<<<dim3(N_NODES / 256, N_NODES / 64), 256, 0, stream>>>(zarr, out + (size_t)N_NODES * NC);
}